// Round 6
// baseline (150.967 us; speedup 1.0000x reference)
//
#include <hip/hip_runtime.h>

typedef unsigned short u16;
typedef unsigned int u32;
typedef __bf16 bf16x8 __attribute__((ext_vector_type(8)));
typedef float f32x4 __attribute__((ext_vector_type(4)));
typedef u32 u32x4 __attribute__((ext_vector_type(4)));

#define AS1 __attribute__((address_space(1)))
#define AS3 __attribute__((address_space(3)))

__device__ __align__(16) u16 g_kT[27 * 64 * 64];

__device__ __forceinline__ u16 f2bf(float f) {
    unsigned int u = __float_as_uint(f);
    u += 0x7FFFu + ((u >> 16) & 1u);   // RNE
    return (u16)(u >> 16);
}

__device__ __forceinline__ u32 pack_bf(float a, float b) {
    u32 ua = __float_as_uint(a) + 0x8000u;
    u32 ub = __float_as_uint(b) + 0x8000u;
    return __builtin_amdgcn_perm(ub, ua, 0x07060302u);
}

// ---------------------------------------------------------------------------
// Build kT[27][64][64] (+ fold self-connection into center tap).
// ---------------------------------------------------------------------------
__global__ __launch_bounds__(64) void build_k(
    const float* __restrict__ Wsc0, const float* __restrict__ Wsc1,
    const float* __restrict__ w1, const float* __restrict__ w2,
    const float* __restrict__ w3, const float* __restrict__ w4)
{
    const int t = blockIdx.x;
    const int c = threadIdx.x;
    const int dx = t / 9 - 1, dy = (t / 3) % 3 - 1, dz = t % 3 - 1;
    const float d = sqrtf((float)(dx * dx + dy * dy + dz * dz));
    const float step = 1.5f / 9.0f;
    float emb[8];
#pragma unroll
    for (int k = 0; k < 8; ++k) {
        float diff = (d - (float)(k + 1) * step) / step;
        float q = diff * diff;
        emb[k] = (q < 1.0f) ? 1.14136f * expf(2.0f - 2.0f / (1.0f - q)) : 0.0f;
    }
    const float dn = fmaxf(d, 1e-12f);
    const float s3 = 1.7320508075688772f;
    const float sh1[3] = { s3 * (float)dx / dn, s3 * (float)dy / dn, s3 * (float)dz / dn };
    const float alpha  = 0.17677669529663687f;
    const float alpha3 = alpha * 0.57735026918962576f;

    u16* outp = &g_kT[(t * 64 + c) * 64];
    if (c < 16) {
        const int o = c;
#pragma unroll
        for (int i = 0; i < 16; ++i) {
            float W1 = 0.f, W4 = 0.f;
#pragma unroll
            for (int k = 0; k < 8; ++k) {
                W1 += emb[k] * w1[k * 256 + i * 16 + o];
                W4 += emb[k] * w4[k * 256 + i * 16 + o];
            }
            W1 *= (1.0f / 27.0f); W4 *= (1.0f / 27.0f);
            float v0 = alpha * W1;
            if (t == 13) v0 += 0.25f * Wsc0[i * 16 + o];
            outp[i] = f2bf(v0);
            const float base = alpha3 * W4;
#pragma unroll
            for (int m = 0; m < 3; ++m) outp[16 + 3 * i + m] = f2bf(base * sh1[m]);
        }
    } else {
        const int o = (c - 16) / 3, nc = (c - 16) % 3;
#pragma unroll
        for (int i = 0; i < 16; ++i) {
            float W2 = 0.f, W3 = 0.f;
#pragma unroll
            for (int k = 0; k < 8; ++k) {
                W2 += emb[k] * w2[k * 256 + i * 16 + o];
                W3 += emb[k] * w3[k * 256 + i * 16 + o];
            }
            W2 *= (1.0f / 27.0f); W3 *= (1.0f / 27.0f);
            outp[i] = f2bf(alpha * W2 * sh1[nc]);
#pragma unroll
            for (int m = 0; m < 3; ++m) {
                float v = (m == nc) ? alpha * W3 : 0.0f;
                if (t == 13 && m == nc) v += 0.25f * Wsc1[i * 16 + o];
                outp[16 + 3 * i + m] = f2bf(v);
            }
        }
    }
}

// ---------------------------------------------------------------------------
// Pre-convert x (fp32) -> xb (bf16) + 4KB zero page.
// ---------------------------------------------------------------------------
__global__ __launch_bounds__(256) void cvt_x(
    const float* __restrict__ x, u16* __restrict__ xb, u32* __restrict__ zp)
{
    const int tid = threadIdx.x;
    if (blockIdx.x == 0) {
        u32x4 z = {0u, 0u, 0u, 0u};
        *reinterpret_cast<u32x4*>(zp + tid * 4) = z;
    }
    const size_t base = ((size_t)blockIdx.x * 256 + tid) * 8;
    const float4* s = reinterpret_cast<const float4*>(x + base);
    float4 v0 = s[0], v1 = s[1];
    u32x4 p;
    p[0] = pack_bf(v0.x, v0.y); p[1] = pack_bf(v0.z, v0.w);
    p[2] = pack_bf(v1.x, v1.y); p[3] = pack_bf(v1.z, v1.w);
    *reinterpret_cast<u32x4*>(xb + base) = p;
}

#define NROWS 408   // 12 * 34

#define ISSUE_B(s, t) \
  { const u16* _p = bT + (t) * 4096; \
    asm volatile("global_load_dwordx4 %0, %4, off\n\t" \
                 "global_load_dwordx4 %1, %4, off offset:64\n\t" \
                 "global_load_dwordx4 %2, %4, off offset:2048\n\t" \
                 "global_load_dwordx4 %3, %4, off offset:2112" \
                 : "=&v"(B##s##0), "=&v"(B##s##1), "=&v"(B##s##2), "=&v"(B##s##3) \
                 : "v"(_p)); }

#define LOAD_A(s, RC) \
  { const int _r  = rbase + (RC); \
    const int _o0 = _r * 128 + ((kg ^ (_r & 7)) << 4); \
    const int _o1 = _o0 ^ 64; \
    A##s##0 = *reinterpret_cast<const bf16x8*>(abase + _o0); \
    A##s##1 = *reinterpret_cast<const bf16x8*>(abase + _o0 + 2048); \
    A##s##2 = *reinterpret_cast<const bf16x8*>(abase + _o1); \
    A##s##3 = *reinterpret_cast<const bf16x8*>(abase + _o1 + 2048); }

#define WAITV(N) \
  asm volatile("s_waitcnt vmcnt(" #N ")" ::: "memory"); \
  __builtin_amdgcn_sched_barrier(0);

#define BC(x) __builtin_bit_cast(bf16x8, x)

#define MFMA8(bs, as) \
  acc00 = __builtin_amdgcn_mfma_f32_16x16x32_bf16(BC(B##bs##0), A##as##0, acc00, 0,0,0); \
  acc01 = __builtin_amdgcn_mfma_f32_16x16x32_bf16(BC(B##bs##2), A##as##0, acc01, 0,0,0); \
  acc10 = __builtin_amdgcn_mfma_f32_16x16x32_bf16(BC(B##bs##0), A##as##1, acc10, 0,0,0); \
  acc11 = __builtin_amdgcn_mfma_f32_16x16x32_bf16(BC(B##bs##2), A##as##1, acc11, 0,0,0); \
  acc00 = __builtin_amdgcn_mfma_f32_16x16x32_bf16(BC(B##bs##1), A##as##2, acc00, 0,0,0); \
  acc01 = __builtin_amdgcn_mfma_f32_16x16x32_bf16(BC(B##bs##3), A##as##2, acc01, 0,0,0); \
  acc10 = __builtin_amdgcn_mfma_f32_16x16x32_bf16(BC(B##bs##1), A##as##3, acc10, 0,0,0); \
  acc11 = __builtin_amdgcn_mfma_f32_16x16x32_bf16(BC(B##bs##3), A##as##3, acc11, 0,0,0);

// common block decode
#define DECODE_BID() \
    const int bid0 = blockIdx.x; \
    const int bid  = (bid0 & 7) * 256 + (bid0 >> 3); \
    const int b    = bid >> 9; \
    const int X    = (bid >> 4) & 31; \
    const int y0   = (bid & 15) << 1; \
    const int tid  = threadIdx.x; \
    const int wv   = tid >> 6; \
    const int lane = tid & 63;

// staging: 51 chunks x 1KB, LDS linear, source XOR-pre-swizzled
#define STAGE_LDS() \
    { \
        const int rloc = lane >> 3; \
        const int swz  = (lane & 7) ^ rloc; \
        _Pragma("unroll") \
        for (int i = 0; i < 13; ++i) { \
            const int c = wv * 13 + i; \
            if (c < 51) { \
                const int row = c * 8 + rloc; \
                const int rid = row / 34; \
                const int zid = row - rid * 34; \
                const int xin = X + (rid >> 2) - 1; \
                const int yin = y0 + (rid & 3) - 1; \
                const int zin = zid - 1; \
                const bool inb = ((unsigned)xin < 32u) & ((unsigned)yin < 32u) \
                               & ((unsigned)zin < 32u); \
                const u16* src = inb \
                    ? xb + ((size_t)(((b * 32 + xin) * 32 + yin) * 32 + zin) * 64 + swz * 8) \
                    : (const u16*)zp; \
                __builtin_amdgcn_global_load_lds((const AS1 u32*)src, \
                                                 (AS3 u32*)&xt[c * 512], 16, 0, 0); \
            } \
        } \
    } \
    asm volatile("s_waitcnt vmcnt(0)" ::: "memory"); \
    __syncthreads();

// ---------------------------------------------------------------------------
// v3 kernel (real output) — unchanged from round 5.
// ---------------------------------------------------------------------------
__global__ __launch_bounds__(256, 3) void conv_mfma3(
    const u16* __restrict__ xb, const u32* __restrict__ zp,
    float* __restrict__ out)
{
    __shared__ __align__(16) u16 xt[NROWS * 64];
    DECODE_BID()
    const int l15 = lane & 15;
    const int kg  = lane >> 4;
    const int mh  = wv >> 1;
    const int nh  = wv & 1;

    const u16* bT = &g_kT[(nh * 32 + l15) * 64 + kg * 8];

    u32x4 B00, B01, B02, B03, B10, B11, B12, B13, B20, B21, B22, B23;
    bf16x8 A00, A01, A02, A03, A10, A11, A12, A13;

    ISSUE_B(0, 1)
    ISSUE_B(1, 3)

    STAGE_LDS()

    const char* abase = reinterpret_cast<const char*>(xt);
    const int rbase = mh * 34 + l15;

    const f32x4 z4 = {0.f, 0.f, 0.f, 0.f};
    f32x4 acc00 = z4, acc01 = z4, acc10 = z4, acc11 = z4;

    LOAD_A(0, 1)

    ISSUE_B(2, 4)   LOAD_A(1, 34)   WAITV(8)  MFMA8(0, 0)   // t=1
    ISSUE_B(0, 5)   LOAD_A(0, 35)   WAITV(8)  MFMA8(1, 1)   // t=3
    ISSUE_B(1, 7)   LOAD_A(1, 36)   WAITV(8)  MFMA8(2, 0)   // t=4
    ISSUE_B(2, 9)   LOAD_A(0, 69)   WAITV(8)  MFMA8(0, 1)   // t=5
    ISSUE_B(0, 10)  LOAD_A(1, 136)  WAITV(8)  MFMA8(1, 0)   // t=7
    ISSUE_B(1, 11)  LOAD_A(0, 137)  WAITV(8)  MFMA8(2, 1)   // t=9
    ISSUE_B(2, 12)  LOAD_A(1, 138)  WAITV(8)  MFMA8(0, 0)   // t=10
    ISSUE_B(0, 13)  LOAD_A(0, 170)  WAITV(8)  MFMA8(1, 1)   // t=11
    ISSUE_B(1, 14)  LOAD_A(1, 171)  WAITV(8)  MFMA8(2, 0)   // t=12
    ISSUE_B(2, 15)  LOAD_A(0, 172)  WAITV(8)  MFMA8(0, 1)   // t=13
    ISSUE_B(0, 16)  LOAD_A(1, 204)  WAITV(8)  MFMA8(1, 0)   // t=14
    ISSUE_B(1, 17)  LOAD_A(0, 205)  WAITV(8)  MFMA8(2, 1)   // t=15
    ISSUE_B(2, 19)  LOAD_A(1, 206)  WAITV(8)  MFMA8(0, 0)   // t=16
    ISSUE_B(0, 21)  LOAD_A(0, 273)  WAITV(8)  MFMA8(1, 1)   // t=17
    ISSUE_B(1, 22)  LOAD_A(1, 306)  WAITV(8)  MFMA8(2, 0)   // t=19
    ISSUE_B(2, 23)  LOAD_A(0, 307)  WAITV(8)  MFMA8(0, 1)   // t=21
    ISSUE_B(0, 25)  LOAD_A(1, 308)  WAITV(8)  MFMA8(1, 0)   // t=22
                    LOAD_A(0, 341)  WAITV(4)  MFMA8(2, 1)   // t=23
                                    WAITV(0)  MFMA8(0, 0)   // t=25

    float* obase = out + (((b * 32 + X) * 32 + (y0 + mh)) * 32) * 64 + nh * 32 + kg * 4;
    {
        float4 v;
        v.x = acc00[0]; v.y = acc00[1]; v.z = acc00[2]; v.w = acc00[3];
        *reinterpret_cast<float4*>(obase + l15 * 64) = v;
        v.x = acc01[0]; v.y = acc01[1]; v.z = acc01[2]; v.w = acc01[3];
        *reinterpret_cast<float4*>(obase + l15 * 64 + 16) = v;
        v.x = acc10[0]; v.y = acc10[1]; v.z = acc10[2]; v.w = acc10[3];
        *reinterpret_cast<float4*>(obase + (16 + l15) * 64) = v;
        v.x = acc11[0]; v.y = acc11[1]; v.z = acc11[2]; v.w = acc11[3];
        *reinterpret_cast<float4*>(obase + (16 + l15) * 64 + 16) = v;
    }
}

// ---------------------------------------------------------------------------
// PROBE 1: staging phase only.
// ---------------------------------------------------------------------------
__global__ __launch_bounds__(256, 3) void probe_stage(
    const u16* __restrict__ xb, const u32* __restrict__ zp, u32* __restrict__ dump)
{
    __shared__ __align__(16) u16 xt[NROWS * 64];
    DECODE_BID()
    STAGE_LDS()
    u32 s = 0;
    const u32* w = reinterpret_cast<const u32*>(xt);
#pragma unroll
    for (int j = 0; j < 8; ++j) s ^= w[tid + j * 1632];
    if (tid == 0) dump[blockIdx.x] = s;
}

// ---------------------------------------------------------------------------
// PROBE 2: pinned B-pipeline + MFMAs, constant A, no staging.
// ---------------------------------------------------------------------------
__global__ __launch_bounds__(256, 3) void probe_B(u32* __restrict__ dump)
{
    __shared__ __align__(16) u16 xt[NROWS * 64];
    const int tid  = threadIdx.x;
    const int lane = tid & 63;
    const int l15  = lane & 15;
    const int kg   = lane >> 4;
    const int nh   = (tid >> 6) & 1;
    xt[tid] = (u16)tid;           // force LDS allocation (occupancy parity)
    __syncthreads();

    const u16* bT = &g_kT[(nh * 32 + l15) * 64 + kg * 8];
    u32x4 B00, B01, B02, B03, B10, B11, B12, B13, B20, B21, B22, B23;
    const u32 lv = (u32)lane * 0x01010101u;
    const bf16x8 A00 = BC(((u32x4){lv, 0x3f803f80u, 0x3f403f40u, 0x3f003f00u}));
    const bf16x8 A01 = BC(((u32x4){lv ^ 0x11u, 0x3e803e80u, 0x3f803f80u, 0x3f403f40u}));
    const bf16x8 A02 = BC(((u32x4){lv ^ 0x22u, 0x3f403f40u, 0x3e803e80u, 0x3f803f80u}));
    const bf16x8 A03 = BC(((u32x4){lv ^ 0x33u, 0x3f003f00u, 0x3f403f40u, 0x3e803e80u}));
    const bf16x8 A10 = A00, A11 = A01, A12 = A02, A13 = A03;  // slot aliases (consts differ per reg idx)
    (void)A10; (void)A11; (void)A12; (void)A13;

    const f32x4 z4 = {0.f, 0.f, 0.f, 0.f};
    f32x4 acc00 = z4, acc01 = z4, acc10 = z4, acc11 = z4;

    ISSUE_B(0, 1)
    ISSUE_B(1, 3)
    ISSUE_B(2, 4)   WAITV(8)  MFMA8(0, 0)
    ISSUE_B(0, 5)   WAITV(8)  MFMA8(1, 0)
    ISSUE_B(1, 7)   WAITV(8)  MFMA8(2, 0)
    ISSUE_B(2, 9)   WAITV(8)  MFMA8(0, 0)
    ISSUE_B(0, 10)  WAITV(8)  MFMA8(1, 0)
    ISSUE_B(1, 11)  WAITV(8)  MFMA8(2, 0)
    ISSUE_B(2, 12)  WAITV(8)  MFMA8(0, 0)
    ISSUE_B(0, 13)  WAITV(8)  MFMA8(1, 0)
    ISSUE_B(1, 14)  WAITV(8)  MFMA8(2, 0)
    ISSUE_B(2, 15)  WAITV(8)  MFMA8(0, 0)
    ISSUE_B(0, 16)  WAITV(8)  MFMA8(1, 0)
    ISSUE_B(1, 17)  WAITV(8)  MFMA8(2, 0)
    ISSUE_B(2, 19)  WAITV(8)  MFMA8(0, 0)
    ISSUE_B(0, 21)  WAITV(8)  MFMA8(1, 0)
    ISSUE_B(1, 22)  WAITV(8)  MFMA8(2, 0)
    ISSUE_B(2, 23)  WAITV(8)  MFMA8(0, 0)
    ISSUE_B(0, 25)  WAITV(8)  MFMA8(1, 0)
                    WAITV(4)  MFMA8(2, 0)
                    WAITV(0)  MFMA8(0, 0)

    f32x4 r = acc00 + acc01 + acc10 + acc11;
    if (tid == 0) *reinterpret_cast<f32x4*>(dump + (size_t)blockIdx.x * 4) = r;
}

// ---------------------------------------------------------------------------
// PROBE 3: staging + A ds_reads + MFMAs, constant B.
// ---------------------------------------------------------------------------
__global__ __launch_bounds__(256, 3) void probe_A(
    const u16* __restrict__ xb, const u32* __restrict__ zp, u32* __restrict__ dump)
{
    __shared__ __align__(16) u16 xt[NROWS * 64];
    DECODE_BID()
    const int l15 = lane & 15;
    const int kg  = lane >> 4;
    const int mh  = wv >> 1;

    STAGE_LDS()

    const char* abase = reinterpret_cast<const char*>(xt);
    const int rbase = mh * 34 + l15;

    const u32 lv = (u32)lane * 0x01010101u;
    const u32x4 B00 = {lv, 0x3f803f80u, 0x3f403f40u, 0x3f003f00u};
    const u32x4 B01 = {lv ^ 0x44u, 0x3e803e80u, 0x3f803f80u, 0x3f403f40u};
    const u32x4 B02 = {lv ^ 0x55u, 0x3f403f40u, 0x3e803e80u, 0x3f803f80u};
    const u32x4 B03 = {lv ^ 0x66u, 0x3f003f00u, 0x3f403f40u, 0x3e803e80u};

    bf16x8 A00, A01, A02, A03, A10, A11, A12, A13;
    const f32x4 z4 = {0.f, 0.f, 0.f, 0.f};
    f32x4 acc00 = z4, acc01 = z4, acc10 = z4, acc11 = z4;

    LOAD_A(0, 1)
    LOAD_A(1, 34)   MFMA8(0, 0)
    LOAD_A(0, 35)   MFMA8(0, 1)
    LOAD_A(1, 36)   MFMA8(0, 0)
    LOAD_A(0, 69)   MFMA8(0, 1)
    LOAD_A(1, 136)  MFMA8(0, 0)
    LOAD_A(0, 137)  MFMA8(0, 1)
    LOAD_A(1, 138)  MFMA8(0, 0)
    LOAD_A(0, 170)  MFMA8(0, 1)
    LOAD_A(1, 171)  MFMA8(0, 0)
    LOAD_A(0, 172)  MFMA8(0, 1)
    LOAD_A(1, 204)  MFMA8(0, 0)
    LOAD_A(0, 205)  MFMA8(0, 1)
    LOAD_A(1, 206)  MFMA8(0, 0)
    LOAD_A(0, 273)  MFMA8(0, 1)
    LOAD_A(1, 306)  MFMA8(0, 0)
    LOAD_A(0, 307)  MFMA8(0, 1)
    LOAD_A(1, 308)  MFMA8(0, 0)
    LOAD_A(0, 341)  MFMA8(0, 1)
                    MFMA8(0, 0)

    f32x4 r = acc00 + acc01 + acc10 + acc11;
    if (tid == 0) *reinterpret_cast<f32x4*>(dump + (size_t)blockIdx.x * 4) = r;
}

// ---------------------------------------------------------------------------
// Fallback (fp32 staging through VGPRs), used only if ws too small.
// ---------------------------------------------------------------------------
#define ZS 68

__global__ __launch_bounds__(256, 2) void conv_mfma_fb(
    const float* __restrict__ x, float* __restrict__ out)
{
    __shared__ __align__(16) u16 xt[NROWS * ZS];
    const int bid0 = blockIdx.x;
    const int bid  = (bid0 & 7) * 256 + (bid0 >> 3);
    const int b   = bid >> 9;
    const int X   = (bid >> 4) & 31;
    const int y0  = (bid & 15) << 1;
    const int tid = threadIdx.x;

    {
        const int pr = tid >> 2;
        const int q  = tid & 3;
#pragma unroll
        for (int pass = 0; pass < 7; ++pass) {
            const int idx = pass * 64 + pr;
            if (idx < NROWS) {
                const int rid = idx / 34;
                const int zid = idx - rid * 34;
                const int xin = X + (rid >> 2) - 1;
                const int yin = y0 + (rid & 3) - 1;
                const int zin = zid - 1;
                u32x4 p0 = {0u,0u,0u,0u}, p1 = {0u,0u,0u,0u};
                if ((unsigned)xin < 32u && (unsigned)yin < 32u && (unsigned)zin < 32u) {
                    const float4* src = reinterpret_cast<const float4*>(
                        x + ((((b * 32 + xin) * 32 + yin) * 32 + zin) * 64 + q * 16));
                    float4 v0 = src[0], v1 = src[1], v2 = src[2], v3 = src[3];
                    p0[0] = pack_bf(v0.x, v0.y); p0[1] = pack_bf(v0.z, v0.w);
                    p0[2] = pack_bf(v1.x, v1.y); p0[3] = pack_bf(v1.z, v1.w);
                    p1[0] = pack_bf(v2.x, v2.y); p1[1] = pack_bf(v2.z, v2.w);
                    p1[2] = pack_bf(v3.x, v3.y); p1[3] = pack_bf(v3.z, v3.w);
                }
                u16* dst = &xt[idx * ZS + q * 16];
                *reinterpret_cast<u32x4*>(dst)     = p0;
                *reinterpret_cast<u32x4*>(dst + 8) = p1;
            }
        }
    }
    __syncthreads();

    const int w    = tid >> 6;
    const int lane = tid & 63;
    const int l15  = lane & 15;
    const int kg   = lane >> 4;
    const int mh   = w >> 1;
    const int nh   = w & 1;
    const int chb  = kg * 8;

    const u16* abase = &xt[l15 * ZS + chb];
    const u16* bbase = &g_kT[(nh * 32 + l15) * 64 + chb];

    const f32x4 z4 = {0.f, 0.f, 0.f, 0.f};
    f32x4 acc[2][2] = {{z4, z4}, {z4, z4}};

    constexpr int NT = 19;
    constexpr int TAPS[NT] = {1,3,4,5,7,9,10,11,12,13,14,15,16,17,19,21,22,23,25};

#pragma unroll
    for (int ti = 0; ti < NT; ++ti) {
        const int t = TAPS[ti];
        const int dxt = t / 9, dyt = (t / 3) % 3, dzt = t % 3;
        const int rid = dxt * 4 + mh + dyt;
        bf16x8 bfr[4], afr[4];
#pragma unroll
        for (int kb = 0; kb < 2; ++kb)
#pragma unroll
        for (int nt = 0; nt < 2; ++nt)
            bfr[kb*2+nt] = *reinterpret_cast<const bf16x8*>(
                bbase + (t * 64 + nt * 16) * 64 + kb * 32);
#pragma unroll
        for (int kb = 0; kb < 2; ++kb)
#pragma unroll
        for (int mt = 0; mt < 2; ++mt)
            afr[kb*2+mt] = *reinterpret_cast<const bf16x8*>(
                abase + (rid * 34 + dzt + mt * 16) * ZS + kb * 32);
#pragma unroll
        for (int kb = 0; kb < 2; ++kb)
#pragma unroll
        for (int mt = 0; mt < 2; ++mt)
#pragma unroll
        for (int nt = 0; nt < 2; ++nt)
            acc[mt][nt] = __builtin_amdgcn_mfma_f32_16x16x32_bf16(
                bfr[kb*2+nt], afr[kb*2+mt], acc[mt][nt], 0, 0, 0);
    }

    float* obase = out + (((b * 32 + X) * 32 + (y0 + mh)) * 32) * 64 + nh * 32 + kg * 4;
#pragma unroll
    for (int mt = 0; mt < 2; ++mt)
#pragma unroll
        for (int nt = 0; nt < 2; ++nt) {
            float4 v;
            v.x = acc[mt][nt][0]; v.y = acc[mt][nt][1];
            v.z = acc[mt][nt][2]; v.w = acc[mt][nt][3];
            *reinterpret_cast<float4*>(obase + (mt * 16 + l15) * 64 + nt * 16) = v;
        }
}

extern "C" void kernel_launch(void* const* d_in, const int* in_sizes, int n_in,
                              void* d_out, int out_size, void* d_ws, size_t ws_size,
                              hipStream_t stream)
{
    const float* x    = (const float*)d_in[0];
    const float* Wsc0 = (const float*)d_in[1];
    const float* Wsc1 = (const float*)d_in[2];
    const float* w1   = (const float*)d_in[3];
    const float* w2   = (const float*)d_in[4];
    const float* w3   = (const float*)d_in[5];
    const float* w4   = (const float*)d_in[6];
    float* out = (float*)d_out;

    build_k<<<dim3(27), dim3(64), 0, stream>>>(Wsc0, Wsc1, w1, w2, w3, w4);

    const size_t xb_bytes = (size_t)4 * 32 * 32 * 32 * 64 * 2;   // 16.8 MB
    const size_t need_probe = 4096 + xb_bytes + 262144;
    const size_t need_min   = 4096 + xb_bytes;
    if (ws_size >= need_min) {
        u32* zp = (u32*)d_ws;
        u16* xb = (u16*)((char*)d_ws + 4096);
        cvt_x<<<dim3(4096), dim3(256), 0, stream>>>(x, xb, zp);
        if (ws_size >= need_probe) {
            char* dumpc = (char*)d_ws + 4096 + xb_bytes;
            probe_stage<<<dim3(768), dim3(256), 0, stream>>>(xb, zp, (u32*)dumpc);
            probe_B    <<<dim3(768), dim3(256), 0, stream>>>((u32*)(dumpc + 65536));
            probe_A    <<<dim3(768), dim3(256), 0, stream>>>(xb, zp, (u32*)(dumpc + 131072));
            conv_mfma3 <<<dim3(256), dim3(256), 0, stream>>>(xb, zp, out);  // 1 blk/CU isolation
        }
        conv_mfma3<<<dim3(2048), dim3(256), 0, stream>>>(xb, zp, out);
    } else {
        conv_mfma_fb<<<dim3(2048), dim3(256), 0, stream>>>(x, out);
    }
}

// Round 7
// 56.775 us; speedup vs baseline: 2.6590x; 2.6590x over previous
//
#include <hip/hip_runtime.h>

typedef unsigned short u16;
typedef unsigned int u32;
typedef __bf16 bf16x8 __attribute__((ext_vector_type(8)));
typedef float f32x4 __attribute__((ext_vector_type(4)));
typedef u32 u32x4 __attribute__((ext_vector_type(4)));

#define AS1 __attribute__((address_space(1)))
#define AS3 __attribute__((address_space(3)))

// kT[t][c][r]  (fallback kernel layout)
__device__ __align__(16) u16 g_kT[27 * 64 * 64];
// kTr[((t*2+nh)*2+nt)*2+kb][lane][j] : per-lane-ordered repack -> every
// B-load is one fully-contiguous 1KB wave read (8 fully-used cachelines).
__device__ __align__(16) u16 g_kTr[27 * 8 * 512];

__device__ __forceinline__ u16 f2bf(float f) {
    unsigned int u = __float_as_uint(f);
    u += 0x7FFFu + ((u >> 16) & 1u);   // RNE
    return (u16)(u >> 16);
}

__device__ __forceinline__ u32 pack_bf(float a, float b) {
    u32 ua = __float_as_uint(a) + 0x8000u;
    u32 ub = __float_as_uint(b) + 0x8000u;
    return __builtin_amdgcn_perm(ub, ua, 0x07060302u);
}

// ---------------------------------------------------------------------------
// Build kT + repacked kTr (+ fold self-connection into center tap).
// ---------------------------------------------------------------------------
__global__ __launch_bounds__(64) void build_k(
    const float* __restrict__ Wsc0, const float* __restrict__ Wsc1,
    const float* __restrict__ w1, const float* __restrict__ w2,
    const float* __restrict__ w3, const float* __restrict__ w4)
{
    const int t = blockIdx.x;
    const int c = threadIdx.x;
    const int dx = t / 9 - 1, dy = (t / 3) % 3 - 1, dz = t % 3 - 1;
    const float d = sqrtf((float)(dx * dx + dy * dy + dz * dz));
    const float step = 1.5f / 9.0f;
    float emb[8];
#pragma unroll
    for (int k = 0; k < 8; ++k) {
        float diff = (d - (float)(k + 1) * step) / step;
        float q = diff * diff;
        emb[k] = (q < 1.0f) ? 1.14136f * expf(2.0f - 2.0f / (1.0f - q)) : 0.0f;
    }
    const float dn = fmaxf(d, 1e-12f);
    const float s3 = 1.7320508075688772f;
    const float sh1[3] = { s3 * (float)dx / dn, s3 * (float)dy / dn, s3 * (float)dz / dn };
    const float alpha  = 0.17677669529663687f;
    const float alpha3 = alpha * 0.57735026918962576f;

    u16* outp = &g_kT[(t * 64 + c) * 64];
    const int base2 = ((t * 2 + (c >> 5)) * 2 + ((c >> 4) & 1)) * 2;
    const int l15c  = c & 15;
    auto put = [&](int r, float v) {
        u16 h = f2bf(v);
        outp[r] = h;
        g_kTr[(base2 + (r >> 5)) * 512 + (((r >> 3) & 3) * 16 + l15c) * 8 + (r & 7)] = h;
    };

    if (c < 16) {
        const int o = c;
#pragma unroll
        for (int i = 0; i < 16; ++i) {
            float W1 = 0.f, W4 = 0.f;
#pragma unroll
            for (int k = 0; k < 8; ++k) {
                W1 += emb[k] * w1[k * 256 + i * 16 + o];
                W4 += emb[k] * w4[k * 256 + i * 16 + o];
            }
            W1 *= (1.0f / 27.0f); W4 *= (1.0f / 27.0f);
            float v0 = alpha * W1;
            if (t == 13) v0 += 0.25f * Wsc0[i * 16 + o];
            put(i, v0);
            const float base = alpha3 * W4;
#pragma unroll
            for (int m = 0; m < 3; ++m) put(16 + 3 * i + m, base * sh1[m]);
        }
    } else {
        const int o = (c - 16) / 3, nc = (c - 16) % 3;
#pragma unroll
        for (int i = 0; i < 16; ++i) {
            float W2 = 0.f, W3 = 0.f;
#pragma unroll
            for (int k = 0; k < 8; ++k) {
                W2 += emb[k] * w2[k * 256 + i * 16 + o];
                W3 += emb[k] * w3[k * 256 + i * 16 + o];
            }
            W2 *= (1.0f / 27.0f); W3 *= (1.0f / 27.0f);
            put(i, alpha * W2 * sh1[nc]);
#pragma unroll
            for (int m = 0; m < 3; ++m) {
                float v = (m == nc) ? alpha * W3 : 0.0f;
                if (t == 13 && m == nc) v += 0.25f * Wsc1[i * 16 + o];
                put(16 + 3 * i + m, v);
            }
        }
    }
}

// ---------------------------------------------------------------------------
// Pre-convert x (fp32) -> xb (bf16) + 4KB zero page.
// ---------------------------------------------------------------------------
__global__ __launch_bounds__(256) void cvt_x(
    const float* __restrict__ x, u16* __restrict__ xb, u32* __restrict__ zp)
{
    const int tid = threadIdx.x;
    if (blockIdx.x == 0) {
        u32x4 z = {0u, 0u, 0u, 0u};
        *reinterpret_cast<u32x4*>(zp + tid * 4) = z;
    }
    const size_t base = ((size_t)blockIdx.x * 256 + tid) * 8;
    const float4* s = reinterpret_cast<const float4*>(x + base);
    float4 v0 = s[0], v1 = s[1];
    u32x4 p;
    p[0] = pack_bf(v0.x, v0.y); p[1] = pack_bf(v0.z, v0.w);
    p[2] = pack_bf(v1.x, v1.y); p[3] = pack_bf(v1.z, v1.w);
    *reinterpret_cast<u32x4*>(xb + base) = p;
}

// ---------------------------------------------------------------------------
// v4: block = (b, X, 4y), 256 thr / 4 waves. Wave (yh, nh): M = 2y x 32z = 64
// positions, N = 32 ch. B from repacked kTr (contiguous 1KB loads, dist-2
// pinned pipeline); A from 78.8KB dynamic-LDS x-tile (612 rows, XOR-swizzled).
// ---------------------------------------------------------------------------
#define NROWS4 612    // 3 dx * 6 y * 34 z
#define NCHUNK 77     // ceil(612/8)
#define LDSB   (NCHUNK * 1024)

#define ISSUE_B(s, t) \
  { const char* _p = bTr + (t) * 8192; \
    asm volatile("global_load_dwordx4 %0, %4, off\n\t" \
                 "global_load_dwordx4 %1, %4, off offset:1024\n\t" \
                 "global_load_dwordx4 %2, %4, off offset:2048\n\t" \
                 "global_load_dwordx4 %3, %4, off offset:3072" \
                 : "=&v"(B##s##0), "=&v"(B##s##1), "=&v"(B##s##2), "=&v"(B##s##3) \
                 : "v"(_p)); }

// r = rbase + RCC ; granule XOR-swizzle matches staging layout.
#define LOADA2(s, i0, i1, RCC) { \
  const int _r  = rbase + (RCC); \
  const int _o0 = _r * 128 + ((kg ^ (_r & 7)) << 4); \
  A##s##i0 = *reinterpret_cast<const bf16x8*>(abase + _o0); \
  A##s##i1 = *reinterpret_cast<const bf16x8*>(abase + (_o0 ^ 64)); }

#define RCC4(T, YY, MT) ((((T)/9)*6 + (YY) + (((T)/3)%3))*34 + ((T)%3) + (MT)*16)

#define LOAD_A8(s, T) \
  LOADA2(s, 0, 1, RCC4(T,0,0)) \
  LOADA2(s, 2, 3, RCC4(T,0,1)) \
  LOADA2(s, 4, 5, RCC4(T,1,0)) \
  LOADA2(s, 6, 7, RCC4(T,1,1))

#define WAITV(N) \
  asm volatile("s_waitcnt vmcnt(" #N ")" ::: "memory"); \
  __builtin_amdgcn_sched_barrier(0);

#define BC(x) __builtin_bit_cast(bf16x8, x)

// acc{yy}{mt}{nt}; B idx = nt*2+kb; A idx = yy*4+mt*2+kb
#define MFMA16(bs, as) \
  acc000 = __builtin_amdgcn_mfma_f32_16x16x32_bf16(BC(B##bs##0), A##as##0, acc000, 0,0,0); \
  acc001 = __builtin_amdgcn_mfma_f32_16x16x32_bf16(BC(B##bs##2), A##as##0, acc001, 0,0,0); \
  acc010 = __builtin_amdgcn_mfma_f32_16x16x32_bf16(BC(B##bs##0), A##as##2, acc010, 0,0,0); \
  acc011 = __builtin_amdgcn_mfma_f32_16x16x32_bf16(BC(B##bs##2), A##as##2, acc011, 0,0,0); \
  acc100 = __builtin_amdgcn_mfma_f32_16x16x32_bf16(BC(B##bs##0), A##as##4, acc100, 0,0,0); \
  acc101 = __builtin_amdgcn_mfma_f32_16x16x32_bf16(BC(B##bs##2), A##as##4, acc101, 0,0,0); \
  acc110 = __builtin_amdgcn_mfma_f32_16x16x32_bf16(BC(B##bs##0), A##as##6, acc110, 0,0,0); \
  acc111 = __builtin_amdgcn_mfma_f32_16x16x32_bf16(BC(B##bs##2), A##as##6, acc111, 0,0,0); \
  acc000 = __builtin_amdgcn_mfma_f32_16x16x32_bf16(BC(B##bs##1), A##as##1, acc000, 0,0,0); \
  acc001 = __builtin_amdgcn_mfma_f32_16x16x32_bf16(BC(B##bs##3), A##as##1, acc001, 0,0,0); \
  acc010 = __builtin_amdgcn_mfma_f32_16x16x32_bf16(BC(B##bs##1), A##as##3, acc010, 0,0,0); \
  acc011 = __builtin_amdgcn_mfma_f32_16x16x32_bf16(BC(B##bs##3), A##as##3, acc011, 0,0,0); \
  acc100 = __builtin_amdgcn_mfma_f32_16x16x32_bf16(BC(B##bs##1), A##as##5, acc100, 0,0,0); \
  acc101 = __builtin_amdgcn_mfma_f32_16x16x32_bf16(BC(B##bs##3), A##as##5, acc101, 0,0,0); \
  acc110 = __builtin_amdgcn_mfma_f32_16x16x32_bf16(BC(B##bs##1), A##as##7, acc110, 0,0,0); \
  acc111 = __builtin_amdgcn_mfma_f32_16x16x32_bf16(BC(B##bs##3), A##as##7, acc111, 0,0,0);

__global__ __launch_bounds__(256, 2) void conv_mfma4(
    const u16* __restrict__ xb, const u32* __restrict__ zp,
    float* __restrict__ out)
{
    extern __shared__ u16 xt[];   // LDSB bytes

    const int bid0 = blockIdx.x;
    const int bid  = (bid0 & 7) * 128 + (bid0 >> 3);   // XCD-contiguous panels
    const int b    = bid >> 8;
    const int X    = (bid >> 3) & 31;
    const int y0   = (bid & 7) << 2;
    const int tid  = threadIdx.x;
    const int wv   = tid >> 6;
    const int lane = tid & 63;
    const int l15  = lane & 15;
    const int kg   = lane >> 4;
    const int yh   = wv >> 1;
    const int nh   = wv & 1;

    const char* bTr = (const char*)g_kTr + nh * 4096 + lane * 16;

    u32x4 B00, B01, B02, B03, B10, B11, B12, B13, B20, B21, B22, B23;
    bf16x8 A00, A01, A02, A03, A04, A05, A06, A07;
    bf16x8 A10, A11, A12, A13, A14, A15, A16, A17;

    // prologue B: taps 1, 3 in flight before staging; drained with it
    ISSUE_B(0, 1)
    ISSUE_B(1, 3)

    // ---- staging: 77 chunks x 1KB; rows (dx*6 + yi)*34 + zid, XOR-swizzled ----
    {
        const int rloc = lane >> 3;
        const int swz  = (lane & 7) ^ rloc;
#pragma unroll
        for (int i = 0; i < 20; ++i) {
            const int c = wv + i * 4;
            if (c < NCHUNK) {
                const int row = c * 8 + rloc;
                const int dxx = row / 204;
                const int rem = row - dxx * 204;
                const int yi  = rem / 34;
                const int zid = rem - yi * 34;
                const int xin = X + dxx - 1;
                const int yin = y0 + yi - 1;
                const int zin = zid - 1;
                const bool inb = (row < NROWS4) & ((unsigned)xin < 32u)
                               & ((unsigned)yin < 32u) & ((unsigned)zin < 32u);
                const u16* src = inb
                    ? xb + ((size_t)(((b * 32 + xin) * 32 + yin) * 32 + zin) * 64 + swz * 8)
                    : (const u16*)zp;
                __builtin_amdgcn_global_load_lds((const AS1 u32*)src,
                                                 (AS3 u32*)&xt[c * 512], 16, 0, 0);
            }
        }
    }
    asm volatile("s_waitcnt vmcnt(0)" ::: "memory");
    __syncthreads();

    const char* abase = reinterpret_cast<const char*>(xt);
    const int rbase = yh * 68 + l15;     // + RCC4(t,yy,mt) at compile time

    const f32x4 z4 = {0.f, 0.f, 0.f, 0.f};
    f32x4 acc000 = z4, acc001 = z4, acc010 = z4, acc011 = z4;
    f32x4 acc100 = z4, acc101 = z4, acc110 = z4, acc111 = z4;

    LOAD_A8(0, 1)

    // taps {1,3,4,5,7,9,10,11,12,13,14,15,16,17,19,21,22,23,25}
    ISSUE_B(2, 4)   LOAD_A8(1, 3)   WAITV(8)  MFMA16(0, 0)   // t=1
    ISSUE_B(0, 5)   LOAD_A8(0, 4)   WAITV(8)  MFMA16(1, 1)   // t=3
    ISSUE_B(1, 7)   LOAD_A8(1, 5)   WAITV(8)  MFMA16(2, 0)   // t=4
    ISSUE_B(2, 9)   LOAD_A8(0, 7)   WAITV(8)  MFMA16(0, 1)   // t=5
    ISSUE_B(0, 10)  LOAD_A8(1, 9)   WAITV(8)  MFMA16(1, 0)   // t=7
    ISSUE_B(1, 11)  LOAD_A8(0, 10)  WAITV(8)  MFMA16(2, 1)   // t=9
    ISSUE_B(2, 12)  LOAD_A8(1, 11)  WAITV(8)  MFMA16(0, 0)   // t=10
    ISSUE_B(0, 13)  LOAD_A8(0, 12)  WAITV(8)  MFMA16(1, 1)   // t=11
    ISSUE_B(1, 14)  LOAD_A8(1, 13)  WAITV(8)  MFMA16(2, 0)   // t=12
    ISSUE_B(2, 15)  LOAD_A8(0, 14)  WAITV(8)  MFMA16(0, 1)   // t=13
    ISSUE_B(0, 16)  LOAD_A8(1, 15)  WAITV(8)  MFMA16(1, 0)   // t=14
    ISSUE_B(1, 17)  LOAD_A8(0, 16)  WAITV(8)  MFMA16(2, 1)   // t=15
    ISSUE_B(2, 19)  LOAD_A8(1, 17)  WAITV(8)  MFMA16(0, 0)   // t=16
    ISSUE_B(0, 21)  LOAD_A8(0, 19)  WAITV(8)  MFMA16(1, 1)   // t=17
    ISSUE_B(1, 22)  LOAD_A8(1, 21)  WAITV(8)  MFMA16(2, 0)   // t=19
    ISSUE_B(2, 23)  LOAD_A8(0, 22)  WAITV(8)  MFMA16(0, 1)   // t=21
    ISSUE_B(0, 25)  LOAD_A8(1, 23)  WAITV(8)  MFMA16(1, 0)   // t=22
                    LOAD_A8(0, 25)  WAITV(4)  MFMA16(2, 1)   // t=23
                                    WAITV(0)  MFMA16(0, 0)   // t=25

    // ---- epilogue: z = mt*16+l15, ch = nh*32 + nt*16 + kg*4, y = y0+yh*2+yy ----
    float* obase = out + (((size_t)(b * 32 + X) * 32 + (y0 + yh * 2)) * 32) * 64
                 + nh * 32 + kg * 4;
    *reinterpret_cast<f32x4*>(obase + l15 * 64)               = acc000;
    *reinterpret_cast<f32x4*>(obase + l15 * 64 + 16)          = acc001;
    *reinterpret_cast<f32x4*>(obase + (16 + l15) * 64)        = acc010;
    *reinterpret_cast<f32x4*>(obase + (16 + l15) * 64 + 16)   = acc011;
    *reinterpret_cast<f32x4*>(obase + 2048 + l15 * 64)        = acc100;
    *reinterpret_cast<f32x4*>(obase + 2048 + l15 * 64 + 16)   = acc101;
    *reinterpret_cast<f32x4*>(obase + 2048 + (16 + l15) * 64) = acc110;
    *reinterpret_cast<f32x4*>(obase + 2048 + (16 + l15) * 64 + 16) = acc111;
}

// ---------------------------------------------------------------------------
// Fallback (fp32 staging through VGPRs, old g_kT layout), if ws too small.
// ---------------------------------------------------------------------------
#define ZS 68
#define NROWS 408

__global__ __launch_bounds__(256, 2) void conv_mfma_fb(
    const float* __restrict__ x, float* __restrict__ out)
{
    __shared__ __align__(16) u16 xts[NROWS * ZS];
    const int bid0 = blockIdx.x;
    const int bid  = (bid0 & 7) * 256 + (bid0 >> 3);
    const int b   = bid >> 9;
    const int X   = (bid >> 4) & 31;
    const int y0  = (bid & 15) << 1;
    const int tid = threadIdx.x;

    {
        const int pr = tid >> 2;
        const int q  = tid & 3;
#pragma unroll
        for (int pass = 0; pass < 7; ++pass) {
            const int idx = pass * 64 + pr;
            if (idx < NROWS) {
                const int rid = idx / 34;
                const int zid = idx - rid * 34;
                const int xin = X + (rid >> 2) - 1;
                const int yin = y0 + (rid & 3) - 1;
                const int zin = zid - 1;
                u32x4 p0 = {0u,0u,0u,0u}, p1 = {0u,0u,0u,0u};
                if ((unsigned)xin < 32u && (unsigned)yin < 32u && (unsigned)zin < 32u) {
                    const float4* src = reinterpret_cast<const float4*>(
                        x + ((((b * 32 + xin) * 32 + yin) * 32 + zin) * 64 + q * 16));
                    float4 v0 = src[0], v1 = src[1], v2 = src[2], v3 = src[3];
                    p0[0] = pack_bf(v0.x, v0.y); p0[1] = pack_bf(v0.z, v0.w);
                    p0[2] = pack_bf(v1.x, v1.y); p0[3] = pack_bf(v1.z, v1.w);
                    p1[0] = pack_bf(v2.x, v2.y); p1[1] = pack_bf(v2.z, v2.w);
                    p1[2] = pack_bf(v3.x, v3.y); p1[3] = pack_bf(v3.z, v3.w);
                }
                u16* dst = &xts[idx * ZS + q * 16];
                *reinterpret_cast<u32x4*>(dst)     = p0;
                *reinterpret_cast<u32x4*>(dst + 8) = p1;
            }
        }
    }
    __syncthreads();

    const int w    = tid >> 6;
    const int lane = tid & 63;
    const int l15  = lane & 15;
    const int kg   = lane >> 4;
    const int mh   = w >> 1;
    const int nh   = w & 1;
    const int chb  = kg * 8;

    const u16* abase = &xts[l15 * ZS + chb];
    const u16* bbase = &g_kT[(nh * 32 + l15) * 64 + chb];

    const f32x4 z4 = {0.f, 0.f, 0.f, 0.f};
    f32x4 acc[2][2] = {{z4, z4}, {z4, z4}};

    constexpr int NT = 19;
    constexpr int TAPS[NT] = {1,3,4,5,7,9,10,11,12,13,14,15,16,17,19,21,22,23,25};

#pragma unroll
    for (int ti = 0; ti < NT; ++ti) {
        const int t = TAPS[ti];
        const int dxt = t / 9, dyt = (t / 3) % 3, dzt = t % 3;
        const int rid = dxt * 4 + mh + dyt;
        bf16x8 bfr[4], afr[4];
#pragma unroll
        for (int kb = 0; kb < 2; ++kb)
#pragma unroll
        for (int nt = 0; nt < 2; ++nt)
            bfr[kb*2+nt] = *reinterpret_cast<const bf16x8*>(
                bbase + (t * 64 + nt * 16) * 64 + kb * 32);
#pragma unroll
        for (int kb = 0; kb < 2; ++kb)
#pragma unroll
        for (int mt = 0; mt < 2; ++mt)
            afr[kb*2+mt] = *reinterpret_cast<const bf16x8*>(
                abase + (rid * 34 + dzt + mt * 16) * ZS + kb * 32);
#pragma unroll
        for (int kb = 0; kb < 2; ++kb)
#pragma unroll
        for (int mt = 0; mt < 2; ++mt)
#pragma unroll
        for (int nt = 0; nt < 2; ++nt)
            acc[mt][nt] = __builtin_amdgcn_mfma_f32_16x16x32_bf16(
                bfr[kb*2+nt], afr[kb*2+mt], acc[mt][nt], 0, 0, 0);
    }

    float* obase = out + (((b * 32 + X) * 32 + (y0 + mh)) * 32) * 64 + nh * 32 + kg * 4;
#pragma unroll
    for (int mt = 0; mt < 2; ++mt)
#pragma unroll
        for (int nt = 0; nt < 2; ++nt) {
            float4 v;
            v.x = acc[mt][nt][0]; v.y = acc[mt][nt][1];
            v.z = acc[mt][nt][2]; v.w = acc[mt][nt][3];
            *reinterpret_cast<float4*>(obase + (mt * 16 + l15) * 64 + nt * 16) = v;
        }
}

extern "C" void kernel_launch(void* const* d_in, const int* in_sizes, int n_in,
                              void* d_out, int out_size, void* d_ws, size_t ws_size,
                              hipStream_t stream)
{
    const float* x    = (const float*)d_in[0];
    const float* Wsc0 = (const float*)d_in[1];
    const float* Wsc1 = (const float*)d_in[2];
    const float* w1   = (const float*)d_in[3];
    const float* w2   = (const float*)d_in[4];
    const float* w3   = (const float*)d_in[5];
    const float* w4   = (const float*)d_in[6];
    float* out = (float*)d_out;

    build_k<<<dim3(27), dim3(64), 0, stream>>>(Wsc0, Wsc1, w1, w2, w3, w4);

    const size_t xb_bytes = (size_t)4 * 32 * 32 * 32 * 64 * 2;   // 16.8 MB
    if (ws_size >= 4096 + xb_bytes) {
        u32* zp = (u32*)d_ws;
        u16* xb = (u16*)((char*)d_ws + 4096);
        cvt_x<<<dim3(4096), dim3(256), 0, stream>>>(x, xb, zp);
        conv_mfma4<<<dim3(1024), dim3(256), LDSB, stream>>>(xb, zp, out);
    } else {
        conv_mfma_fb<<<dim3(2048), dim3(256), 0, stream>>>(x, out);
    }
}